// Round 7
// baseline (255.492 us; speedup 1.0000x reference)
//
#include <hip/hip_runtime.h>
#include <stdint.h>

#define B 4096
#define D 2048
#define BK 128          // k-slab per K-step (fp8 elements; 128 B rows)
#define NITER (D / BK)  // 16
#define BM 64
#define BN 128

typedef unsigned long long ull;
typedef float f32x4 __attribute__((ext_vector_type(4)));
typedef int i32x4 __attribute__((ext_vector_type(4)));  // 16 B LDS read
typedef int i32x8 __attribute__((ext_vector_type(8)));  // 32 B MFMA operand

#define SENT_P 0x00000000FFFFFFFFull  // dist=0.0, ~idx -> "no positive seen"
#define SENT_N (~0ull)                // +inf      -> "no negative seen"

// ---------------- async global->LDS (16B per lane, wave-uniform LDS base) ----
__device__ __forceinline__ void async_copy16(const unsigned char* g, unsigned char* l) {
  __builtin_amdgcn_global_load_lds(
      (const __attribute__((address_space(1))) unsigned int*)g,
      (__attribute__((address_space(3))) unsigned int*)l,
      16, 0, 0);
}

// ---------------- fp32 -> fp8 e4m3 (OCP, RNE) + norms + sentinel init -------
// embq is written in a k-PERMUTED layout (dot products are invariant under a
// uniform k-permutation of both operands). Within each 128 B K-step segment:
//   orig k = s*32 + qp*8 + b  (s=slab 0..3, qp=MFMA lane-group 0..3, b=0..7)
//   stored at pos = qp*32 + s*8 + b   ("q-major")
// so lane-group qp's 32 B for the whole 128-k slab is two 16 B chunks: the
// per-lane operand of mfma_scale_f32_16x16x128. Since A and B use the SAME
// per-lane byte->k semantics, any HW-internal k-mapping cancels in the
// contraction (verified on HW: round-6 passed with absmax 0).
__global__ void k_convert_sq(const float* __restrict__ emb,
                             unsigned char* __restrict__ embq,
                             float* __restrict__ sq,
                             float* __restrict__ rs,
                             ull* __restrict__ bp,
                             ull* __restrict__ bn,
                             float* __restrict__ red_sum,
                             int* __restrict__ red_cnt,
                             int* __restrict__ red_done) {
  const int row = blockIdx.x, t = threadIdx.x;
  const float4* src = (const float4*)(emb + (size_t)row * D);
  float4 v0 = src[2 * t], v1 = src[2 * t + 1];
  float s = v0.x * v0.x + v0.y * v0.y + v0.z * v0.z + v0.w * v0.w
          + v1.x * v1.x + v1.y * v1.y + v1.z * v1.z + v1.w * v1.w;
  float sm = v0.x + v0.y + v0.z + v0.w + v1.x + v1.y + v1.z + v1.w;

  unsigned w0 = __builtin_amdgcn_cvt_pk_fp8_f32(v0.x, v0.y, 0, false);
  w0 = __builtin_amdgcn_cvt_pk_fp8_f32(v0.z, v0.w, w0, true);
  unsigned w1 = __builtin_amdgcn_cvt_pk_fp8_f32(v1.x, v1.y, 0, false);
  w1 = __builtin_amdgcn_cvt_pk_fp8_f32(v1.z, v1.w, w1, true);
  uint2 o; o.x = w0; o.y = w1;
  // thread t holds orig k in [8t, 8t+8): kb = t>>4, s = (t>>2)&3, qp = t&3
  const int pos = ((t >> 4) << 7) | ((t & 3) << 5) | (((t >> 2) & 3) << 3);
  *(uint2*)(embq + (size_t)row * D + pos) = o;

  for (int off = 32; off; off >>= 1) {
    s  += __shfl_down(s, off, 64);
    sm += __shfl_down(sm, off, 64);
  }
  __shared__ float ps[4], pm[4];
  int lane = t & 63, wave = t >> 6;
  if (lane == 0) { ps[wave] = s; pm[wave] = sm; }
  __syncthreads();
  if (t == 0) {
    sq[row] = ps[0] + ps[1] + ps[2] + ps[3];
    rs[row] = pm[0] + pm[1] + pm[2] + pm[3];
    bp[row] = SENT_P;
    bn[row] = SENT_N;
    if (row == 0) { *red_sum = 0.0f; *red_cnt = 0; *red_done = 0; }
  }
}

// ---------------- fused symmetric fp8 GEMM + hard pos/neg selection ---------
// R3 proven structure UNCHANGED (64x128 tiles over the strict upper triangle,
// 1056 blocks, 4 waves as 2x2, single-buffered 24 KB LDS, 2-barrier K-loop —
// inter-block TLP is the latency hider; every intra-block pipeline variant
// measured slower). ONE change vs R3: 8x mfma_scale_f32_16x16x128_f8f6f4
// (unit E8M0 scales = exact same products) replaces 32x 16x16x32 fp8 MFMA:
// 2x the MFMA rate (4661 vs 2047 TF measured), 1/4 the issue slots. Round-6
// regression root-caused to union-induced scratch spill (WRITE_SIZE 9->249
// MB); operands are now built in REGISTERS via __builtin_shufflevector of
// two i32x4 LDS reads — verify WRITE_SIZE ~9 MB this round.
__launch_bounds__(256, 4)
__global__ void k_gemm_select(const unsigned char* __restrict__ embq,
                              const float* __restrict__ sq,
                              const int* __restrict__ labels,
                              ull* __restrict__ best_pos,
                              ull* __restrict__ best_neg) {
  __shared__ __align__(16) unsigned char ldsA[BM * BK];  // 8 KB
  __shared__ __align__(16) unsigned char ldsB[BN * BK];  // 16 KB

  // linear bid -> (by in [0,64), bx in [0,32)) with bx*128+127 > by*64
  int rem = blockIdx.x, p = 0;
  while (rem >= 2 * (32 - p)) { rem -= 2 * (32 - p); ++p; }
  int by = 2 * p;
  int c = 32 - p;
  if (rem >= c) { by += 1; rem -= c; }
  const int bx = p + rem;

  const int tid  = threadIdx.x;
  const int lane = tid & 63;
  const int wave = tid >> 6;
  const int wm = wave >> 1, wn = wave & 1;
  const int q = lane >> 4, m15 = lane & 15;
  const int ibase = by * BM, jbase = bx * BN;

  // b128 fragment read offsets, chunk pair (q*2, q*2+1) = lane-group q's 32 B
  // for the full 128-k slab:  row = wbase + g*16 + m15 ; slot = chunk^(row&7)
  //   byte = row*128 + slot*16
  int aoff[2][2], boff[2][4];
#pragma unroll
  for (int sh = 0; sh < 2; ++sh) {
#pragma unroll
    for (int g = 0; g < 2; ++g) {
      int ra = wm * 32 + g * 16 + m15;
      aoff[sh][g] = ra * BK + (((q * 2 + sh) ^ (ra & 7)) * 16);
    }
#pragma unroll
    for (int g = 0; g < 4; ++g) {
      int rb = wn * 64 + g * 16 + m15;
      boff[sh][g] = rb * BK + (((q * 2 + sh) ^ (rb & 7)) * 16);
    }
  }

  // staging: 6 issues/wave per K-step (2 A + 4 B), 8 rows x 1 KB per issue.
  // LDS dest linear (base + lane*16); global source pre-swizzled so LDS slot
  // `slot` holds global chunk slot^(row&7)  (XOR involution matches reads).
  const int srow = lane >> 3;  // row within 8-row staging group
  const int slot = lane & 7;   // 16B slot within 128B row
  size_t agoff[2], bgoff[4];
  int lasta[2], lastb[4];
#pragma unroll
  for (int pp = 0; pp < 2; ++pp) {
    int r0  = wave * 16 + pp * 8;  // wave-uniform
    int row = r0 + srow;
    agoff[pp] = (size_t)(ibase + row) * D + (slot ^ (row & 7)) * 16;
    lasta[pp] = r0 * BK;
  }
#pragma unroll
  for (int pp = 0; pp < 4; ++pp) {
    int r0  = wave * 32 + pp * 8;  // wave-uniform
    int row = r0 + srow;
    bgoff[pp] = (size_t)(jbase + row) * D + (slot ^ (row & 7)) * 16;
    lastb[pp] = r0 * BK;
  }

  f32x4 acc[2][4];
  const f32x4 z = {0.f, 0.f, 0.f, 0.f};
#pragma unroll
  for (int a = 0; a < 2; ++a)
#pragma unroll
    for (int b = 0; b < 4; ++b) acc[a][b] = z;

  for (int kb = 0; kb < D; kb += BK) {
    __syncthreads();
#pragma unroll
    for (int pp = 0; pp < 2; ++pp)
      async_copy16(embq + agoff[pp] + kb, &ldsA[lasta[pp]]);
#pragma unroll
    for (int pp = 0; pp < 4; ++pp)
      async_copy16(embq + bgoff[pp] + kb, &ldsB[lastb[pp]]);
    __syncthreads();  // compiler emits vmcnt(0) drain before barrier

    // register-built 32 B operands: two i32x4 LDS reads -> shufflevector
    i32x8 fa[2];
#pragma unroll
    for (int g = 0; g < 2; ++g) {
      i32x4 lo = *(const i32x4*)&ldsA[aoff[0][g]];
      i32x4 hi = *(const i32x4*)&ldsA[aoff[1][g]];
      fa[g] = __builtin_shufflevector(lo, hi, 0, 1, 2, 3, 4, 5, 6, 7);
    }
#pragma unroll
    for (int ni = 0; ni < 4; ++ni) {
      i32x4 lo = *(const i32x4*)&ldsB[boff[0][ni]];
      i32x4 hi = *(const i32x4*)&ldsB[boff[1][ni]];
      i32x8 fb = __builtin_shufflevector(lo, hi, 0, 1, 2, 3, 4, 5, 6, 7);
#pragma unroll
      for (int mi = 0; mi < 2; ++mi)
        acc[mi][ni] = __builtin_amdgcn_mfma_scale_f32_16x16x128_f8f6f4(
            fa[mi], fb, acc[mi][ni],
            0 /*cbsz: A=FP8 e4m3*/, 0 /*blgp: B=FP8 e4m3*/,
            0, 0x7F7F7F7Fu /*scale_a = 1.0*/,
            0, 0x7F7F7F7Fu /*scale_b = 1.0*/);
    }
  }

  // ---- epilogue ----
  float sqj[4];
  int labj[4];
#pragma unroll
  for (int ni = 0; ni < 4; ++ni) {
    int jj = jbase + wn * 64 + ni * 16 + m15;
    sqj[ni] = sq[jj];
    labj[ni] = labels[jj];
  }

  ull colBp[4], colBn[4];
#pragma unroll
  for (int ni = 0; ni < 4; ++ni) { colBp[ni] = SENT_P; colBn[ni] = SENT_N; }

#pragma unroll
  for (int mi = 0; mi < 2; ++mi) {
#pragma unroll
    for (int r = 0; r < 4; ++r) {
      const int i = ibase + wm * 32 + mi * 16 + q * 4 + r;  // C/D row=(lane>>4)*4+r
      const float si = sq[i];
      const int li = labels[i];
      ull bp = SENT_P;
      ull bn = SENT_N;
#pragma unroll
      for (int ni = 0; ni < 4; ++ni) {
        int jj = jbase + wn * 64 + ni * 16 + m15;  // C/D col=lane&15
        if (jj > i) {                              // strict upper triangle only
          float dot = acc[mi][ni][r];
          float d2 = si + sqj[ni] - 2.0f * dot;
          float dist = sqrtf(fmaxf(d2, 0.0f));
          ull pv = ((ull)__float_as_uint(dist)) << 32;
          if (labj[ni] == li) {
            ull cr = pv | (unsigned)(~jj);  // max -> smallest idx wins ties
            bp = bp > cr ? bp : cr;
            ull cc = pv | (unsigned)(~i);
            colBp[ni] = colBp[ni] > cc ? colBp[ni] : cc;
          } else {
            ull cr = pv | (unsigned)jj;     // min -> smallest idx wins ties
            bn = bn < cr ? bn : cr;
            ull cc = pv | (unsigned)i;
            colBn[ni] = colBn[ni] < cc ? colBn[ni] : cc;
          }
        }
      }
      // row-i reduction across the 16 column lanes (m15 bits)
#pragma unroll
      for (int off = 1; off <= 8; off <<= 1) {
        ull op = __shfl_xor(bp, off, 64);
        ull on = __shfl_xor(bn, off, 64);
        bp = bp > op ? bp : op;
        bn = bn < on ? bn : on;
      }
      if (m15 == 0) {
        if (bp != SENT_P) atomicMax(&best_pos[i], bp);
        if (bn != SENT_N) atomicMin(&best_neg[i], bn);
      }
    }
  }

  // col-j reduction across the 4 q lane-groups
#pragma unroll
  for (int ni = 0; ni < 4; ++ni) {
    ull cp = colBp[ni], cn = colBn[ni];
#pragma unroll
    for (int off = 16; off <= 32; off <<= 1) {
      ull op = __shfl_xor(cp, off, 64);
      ull on = __shfl_xor(cn, off, 64);
      cp = cp > op ? cp : op;
      cn = cn < on ? cn : on;
    }
    if (q == 0) {
      int j = jbase + wn * 64 + ni * 16 + m15;
      if (cp != SENT_P) atomicMax(&best_pos[j], cp);
      if (cn != SENT_N) atomicMin(&best_neg[j], cn);
    }
  }
}

// ---------------- loss: 16-block partial reduce, last block finalizes -------
__global__ void k_loss_final(const ull* __restrict__ best_pos,
                             const ull* __restrict__ best_neg,
                             const float* __restrict__ rs,
                             float* __restrict__ red_sum,
                             int* __restrict__ red_cnt,
                             int* __restrict__ red_done,
                             float* __restrict__ out) {
  const int i = blockIdx.x * 256 + threadIdx.x;
  float per = 0.0f;
  int v = 0;
  ull bp = best_pos[i], bn = best_neg[i];
  if (bp != SENT_P && bn != SENT_N) {
    unsigned pRaw = ~(unsigned)bp;
    unsigned nRaw = (unsigned)bn;
    int pi = pRaw < (unsigned)B ? (int)pRaw : 0;
    int nj = nRaw < (unsigned)B ? (int)nRaw : 0;
    float distp = __uint_as_float((unsigned)(bp >> 32));
    float distn = __uint_as_float((unsigned)(bn >> 32));
    float ri = rs[i];
    const float e = 1e-6f, de2 = (float)D * 1e-12f;
    float dp2 = distp * distp + 2.0f * e * (ri - rs[pi]) + de2;
    float dn2 = distn * distn + 2.0f * e * (ri - rs[nj]) + de2;
    float dp = sqrtf(fmaxf(dp2, 0.0f));
    float dn = sqrtf(fmaxf(dn2, 0.0f));
    per = fmaxf(dp - dn + 0.3f, 0.0f);
    v = 1;
  }
  for (int off = 32; off; off >>= 1) {
    per += __shfl_down(per, off, 64);
    v   += __shfl_down(v, off, 64);
  }
  __shared__ float pps[4];
  __shared__ int pvs[4];
  int lane = threadIdx.x & 63, wave = threadIdx.x >> 6;
  if (lane == 0) { pps[wave] = per; pvs[wave] = v; }
  __syncthreads();
  if (threadIdx.x == 0) {
    float t = pps[0] + pps[1] + pps[2] + pps[3];
    int cv = pvs[0] + pvs[1] + pvs[2] + pvs[3];
    atomicAdd(red_sum, t);
    atomicAdd(red_cnt, cv);
    __threadfence();
    int old = atomicAdd(red_done, 1);
    if (old == (int)gridDim.x - 1) {
      float s = atomicAdd(red_sum, 0.0f);   // coherent device-scope read
      int cc = atomicAdd(red_cnt, 0);
      out[0] = cc > 0 ? s / (float)cc : 0.0f;
    }
  }
}

// ---------------- launch -----------------------------------------------------
extern "C" void kernel_launch(void* const* d_in, const int* in_sizes, int n_in,
                              void* d_out, int out_size, void* d_ws, size_t ws_size,
                              hipStream_t stream) {
  const float* emb = (const float*)d_in[0];
  const int* labels = (const int*)d_in[1];
  float* out = (float*)d_out;
  char* ws = (char*)d_ws;

  const size_t off_embq = 0;
  const size_t off_sq   = off_embq + (size_t)B * D;       // 8 MiB
  const size_t off_rs   = off_sq + (size_t)B * 4;
  const size_t off_bp   = off_rs + (size_t)B * 4;
  const size_t off_bn   = off_bp + (size_t)B * 8;
  const size_t off_red  = off_bn + (size_t)B * 8;

  unsigned char* embq = (unsigned char*)(ws + off_embq);
  float* sq   = (float*)(ws + off_sq);
  float* rs   = (float*)(ws + off_rs);
  ull* bp     = (ull*)(ws + off_bp);
  ull* bn     = (ull*)(ws + off_bn);
  float* red_sum = (float*)(ws + off_red);
  int* red_cnt   = (int*)(ws + off_red + 4);
  int* red_done  = (int*)(ws + off_red + 8);

  hipLaunchKernelGGL(k_convert_sq, dim3(B), dim3(256), 0, stream,
                     emb, embq, sq, rs, bp, bn, red_sum, red_cnt, red_done);
  hipLaunchKernelGGL(k_gemm_select, dim3(1056), dim3(256), 0, stream,
                     embq, sq, labels, bp, bn);
  hipLaunchKernelGGL(k_loss_final, dim3(B / 256), dim3(256), 0, stream,
                     bp, bn, rs, red_sum, red_cnt, red_done, out);
}

// Round 8
// 195.076 us; speedup vs baseline: 1.3097x; 1.3097x over previous
//
#include <hip/hip_runtime.h>
#include <stdint.h>

#define B 4096
#define D 2048
#define BK 128          // k-slab per K-step (fp8 elements; 128 B rows)
#define NITER (D / BK)  // 16
#define BM 64
#define BN 128

typedef unsigned long long ull;
typedef float f32x4 __attribute__((ext_vector_type(4)));
typedef long v2l __attribute__((ext_vector_type(2)));  // 16 B, 16-B aligned

#define SENT_P 0x00000000FFFFFFFFull  // dist=0.0, ~idx -> "no positive seen"
#define SENT_N (~0ull)                // +inf      -> "no negative seen"

// ---------------- async global->LDS (16B per lane, wave-uniform LDS base) ----
__device__ __forceinline__ void async_copy16(const unsigned char* g, unsigned char* l) {
  __builtin_amdgcn_global_load_lds(
      (const __attribute__((address_space(1))) unsigned int*)g,
      (__attribute__((address_space(3))) unsigned int*)l,
      16, 0, 0);
}

// ---------------- fp32 -> fp8 e4m3 (OCP, RNE) + norms + sentinel init -------
// embq is written in a k-PERMUTED layout (dot products are invariant under a
// uniform k-permutation of both operands). Within each 128 B K-step segment:
//   orig k = s*32 + qp*8 + b  (s=slab 0..3, qp=MFMA lane-group 0..3, b=0..7)
//   stored at pos = qp*32 + s*8 + b   ("q-major")
// so one 16 B chunk c = qp*2 + (s>>1) holds a lane-group's fragments for TWO
// consecutive slabs -> the GEMM reads it with a single ds_read_b128 at the
// conflict-free b128 bank floor.
__global__ void k_convert_sq(const float* __restrict__ emb,
                             unsigned char* __restrict__ embq,
                             float* __restrict__ sq,
                             float* __restrict__ rs,
                             ull* __restrict__ bp,
                             ull* __restrict__ bn,
                             int* __restrict__ gemm_done) {
  const int row = blockIdx.x, t = threadIdx.x;
  const float4* src = (const float4*)(emb + (size_t)row * D);
  float4 v0 = src[2 * t], v1 = src[2 * t + 1];
  float s = v0.x * v0.x + v0.y * v0.y + v0.z * v0.z + v0.w * v0.w
          + v1.x * v1.x + v1.y * v1.y + v1.z * v1.z + v1.w * v1.w;
  float sm = v0.x + v0.y + v0.z + v0.w + v1.x + v1.y + v1.z + v1.w;

  unsigned w0 = __builtin_amdgcn_cvt_pk_fp8_f32(v0.x, v0.y, 0, false);
  w0 = __builtin_amdgcn_cvt_pk_fp8_f32(v0.z, v0.w, w0, true);
  unsigned w1 = __builtin_amdgcn_cvt_pk_fp8_f32(v1.x, v1.y, 0, false);
  w1 = __builtin_amdgcn_cvt_pk_fp8_f32(v1.z, v1.w, w1, true);
  uint2 o; o.x = w0; o.y = w1;
  // thread t holds orig k in [8t, 8t+8): kb = t>>4, s = (t>>2)&3, qp = t&3
  const int pos = ((t >> 4) << 7) | ((t & 3) << 5) | (((t >> 2) & 3) << 3);
  *(uint2*)(embq + (size_t)row * D + pos) = o;

  for (int off = 32; off; off >>= 1) {
    s  += __shfl_down(s, off, 64);
    sm += __shfl_down(sm, off, 64);
  }
  __shared__ float ps[4], pm[4];
  int lane = t & 63, wave = t >> 6;
  if (lane == 0) { ps[wave] = s; pm[wave] = sm; }
  __syncthreads();
  if (t == 0) {
    sq[row] = ps[0] + ps[1] + ps[2] + ps[3];
    rs[row] = pm[0] + pm[1] + pm[2] + pm[3];
    bp[row] = SENT_P;
    bn[row] = SENT_N;
    if (row == 0) *gemm_done = 0;
  }
}

// ---------------- fused symmetric fp8 GEMM + selection + tail loss ----------
// R3 proven structure EXACTLY (64x128 tiles over the strict upper triangle,
// 1056 blocks, 4 waves as 2x2, single-buffered 24 KB LDS, 2-barrier K-loop;
// all 1056 blocks co-resident at 6 blocks/CU so inter-block TLP hides the
// staging drain — every pipeline/tile variant measured slower; scaled-MFMA
// path abandoned after two spill-signature failures). NEW: the final loss is
// fused via a done-counter — the last block to finish re-reads best_pos/
// best_neg with non-destructive device-scope atomics (atomicMax(p,0) returns
// old, writes old — safe vs cross-XCD L2 staleness) and writes the mean.
// Removes one kernel launch + the separate loss kernel.
__launch_bounds__(256, 4)
__global__ void k_gemm_select(const unsigned char* __restrict__ embq,
                              const float* __restrict__ sq,
                              const int* __restrict__ labels,
                              const float* __restrict__ rs,
                              ull* __restrict__ best_pos,
                              ull* __restrict__ best_neg,
                              int* __restrict__ gemm_done,
                              float* __restrict__ out) {
  __shared__ __align__(16) unsigned char ldsA[BM * BK];  // 8 KB
  __shared__ __align__(16) unsigned char ldsB[BN * BK];  // 16 KB

  // linear bid -> (by in [0,64), bx in [0,32)) with bx*128+127 > by*64
  int rem = blockIdx.x, p = 0;
  while (rem >= 2 * (32 - p)) { rem -= 2 * (32 - p); ++p; }
  int by = 2 * p;
  int c = 32 - p;
  if (rem >= c) { by += 1; rem -= c; }
  const int bx = p + rem;

  const int tid  = threadIdx.x;
  const int lane = tid & 63;
  const int wave = tid >> 6;
  const int wm = wave >> 1, wn = wave & 1;
  const int q = lane >> 4, m15 = lane & 15;
  const int ibase = by * BM, jbase = bx * BN;

  // b128 fragment read offsets for slab-pair sh (slabs 2sh, 2sh+1), group g:
  //   row = wbase + g*16 + m15 ; chunk = q*2 + sh ; slot = chunk ^ (row&7)
  //   byte = row*128 + slot*16   (16-B aligned; [0,8)=slab 2sh, [8,16)=2sh+1)
  int aoff[2][2], boff[2][4];
#pragma unroll
  for (int sh = 0; sh < 2; ++sh) {
#pragma unroll
    for (int g = 0; g < 2; ++g) {
      int ra = wm * 32 + g * 16 + m15;
      aoff[sh][g] = ra * BK + (((q * 2 + sh) ^ (ra & 7)) * 16);
    }
#pragma unroll
    for (int g = 0; g < 4; ++g) {
      int rb = wn * 64 + g * 16 + m15;
      boff[sh][g] = rb * BK + (((q * 2 + sh) ^ (rb & 7)) * 16);
    }
  }

  // staging: 6 issues/wave per K-step (2 A + 4 B), 8 rows x 1 KB per issue.
  // LDS dest linear (base + lane*16); global source pre-swizzled so LDS slot
  // `slot` holds global chunk slot^(row&7)  (XOR involution matches reads).
  const int srow = lane >> 3;  // row within 8-row staging group
  const int slot = lane & 7;   // 16B slot within 128B row
  size_t agoff[2], bgoff[4];
  int lasta[2], lastb[4];
#pragma unroll
  for (int pp = 0; pp < 2; ++pp) {
    int r0  = wave * 16 + pp * 8;  // wave-uniform
    int row = r0 + srow;
    agoff[pp] = (size_t)(ibase + row) * D + (slot ^ (row & 7)) * 16;
    lasta[pp] = r0 * BK;
  }
#pragma unroll
  for (int pp = 0; pp < 4; ++pp) {
    int r0  = wave * 32 + pp * 8;  // wave-uniform
    int row = r0 + srow;
    bgoff[pp] = (size_t)(jbase + row) * D + (slot ^ (row & 7)) * 16;
    lastb[pp] = r0 * BK;
  }

  f32x4 acc[2][4];
  const f32x4 z = {0.f, 0.f, 0.f, 0.f};
#pragma unroll
  for (int a = 0; a < 2; ++a)
#pragma unroll
    for (int b = 0; b < 4; ++b) acc[a][b] = z;

  for (int kb = 0; kb < D; kb += BK) {
    __syncthreads();
#pragma unroll
    for (int pp = 0; pp < 2; ++pp)
      async_copy16(embq + agoff[pp] + kb, &ldsA[lasta[pp]]);
#pragma unroll
    for (int pp = 0; pp < 4; ++pp)
      async_copy16(embq + bgoff[pp] + kb, &ldsB[lastb[pp]]);
    __syncthreads();  // compiler emits vmcnt(0) drain before barrier

#pragma unroll
    for (int sh = 0; sh < 2; ++sh) {
      v2l af[2], bf[4];
#pragma unroll
      for (int g = 0; g < 2; ++g) af[g] = *(const v2l*)&ldsA[aoff[sh][g]];
#pragma unroll
      for (int g = 0; g < 4; ++g) bf[g] = *(const v2l*)&ldsB[boff[sh][g]];
#pragma unroll
      for (int mi = 0; mi < 2; ++mi)
#pragma unroll
        for (int ni = 0; ni < 4; ++ni)
          acc[mi][ni] = __builtin_amdgcn_mfma_f32_16x16x32_fp8_fp8(
              af[mi][0], bf[ni][0], acc[mi][ni], 0, 0, 0);
#pragma unroll
      for (int mi = 0; mi < 2; ++mi)
#pragma unroll
        for (int ni = 0; ni < 4; ++ni)
          acc[mi][ni] = __builtin_amdgcn_mfma_f32_16x16x32_fp8_fp8(
              af[mi][1], bf[ni][1], acc[mi][ni], 0, 0, 0);
    }
  }

  // ---- epilogue ----
  float sqj[4];
  int labj[4];
#pragma unroll
  for (int ni = 0; ni < 4; ++ni) {
    int jj = jbase + wn * 64 + ni * 16 + m15;
    sqj[ni] = sq[jj];
    labj[ni] = labels[jj];
  }

  ull colBp[4], colBn[4];
#pragma unroll
  for (int ni = 0; ni < 4; ++ni) { colBp[ni] = SENT_P; colBn[ni] = SENT_N; }

#pragma unroll
  for (int mi = 0; mi < 2; ++mi) {
#pragma unroll
    for (int r = 0; r < 4; ++r) {
      const int i = ibase + wm * 32 + mi * 16 + q * 4 + r;  // C/D row=(lane>>4)*4+r
      const float si = sq[i];
      const int li = labels[i];
      ull bp = SENT_P;
      ull bn = SENT_N;
#pragma unroll
      for (int ni = 0; ni < 4; ++ni) {
        int jj = jbase + wn * 64 + ni * 16 + m15;  // C/D col=lane&15
        if (jj > i) {                              // strict upper triangle only
          float dot = acc[mi][ni][r];
          float d2 = si + sqj[ni] - 2.0f * dot;
          float dist = sqrtf(fmaxf(d2, 0.0f));
          ull pv = ((ull)__float_as_uint(dist)) << 32;
          if (labj[ni] == li) {
            ull cr = pv | (unsigned)(~jj);  // max -> smallest idx wins ties
            bp = bp > cr ? bp : cr;
            ull cc = pv | (unsigned)(~i);
            colBp[ni] = colBp[ni] > cc ? colBp[ni] : cc;
          } else {
            ull cr = pv | (unsigned)jj;     // min -> smallest idx wins ties
            bn = bn < cr ? bn : cr;
            ull cc = pv | (unsigned)i;
            colBn[ni] = colBn[ni] < cc ? colBn[ni] : cc;
          }
        }
      }
      // row-i reduction across the 16 column lanes (m15 bits)
#pragma unroll
      for (int off = 1; off <= 8; off <<= 1) {
        ull op = __shfl_xor(bp, off, 64);
        ull on = __shfl_xor(bn, off, 64);
        bp = bp > op ? bp : op;
        bn = bn < on ? bn : on;
      }
      if (m15 == 0) {
        if (bp != SENT_P) atomicMax(&best_pos[i], bp);
        if (bn != SENT_N) atomicMin(&best_neg[i], bn);
      }
    }
  }

  // col-j reduction across the 4 q lane-groups
#pragma unroll
  for (int ni = 0; ni < 4; ++ni) {
    ull cp = colBp[ni], cn = colBn[ni];
#pragma unroll
    for (int off = 16; off <= 32; off <<= 1) {
      ull op = __shfl_xor(cp, off, 64);
      ull on = __shfl_xor(cn, off, 64);
      cp = cp > op ? cp : op;
      cn = cn < on ? cn : on;
    }
    if (q == 0) {
      int j = jbase + wn * 64 + ni * 16 + m15;
      if (cp != SENT_P) atomicMax(&best_pos[j], cp);
      if (cn != SENT_N) atomicMin(&best_neg[j], cn);
    }
  }

  // ---- fused tail loss: last block to finish computes the final mean ------
  __threadfence();           // make this block's atomics device-visible
  __syncthreads();           // all waves' atomics issued before the count
  __shared__ int sLast;
  if (tid == 0) sLast = (atomicAdd(gemm_done, 1) == (int)gridDim.x - 1);
  __syncthreads();
  if (sLast) {
    float per = 0.0f;
    int v = 0;
    for (int i = tid; i < B; i += 256) {
      // non-destructive device-scope reads: max(old,0) == old for ull
      ull bpv = atomicMax(&best_pos[i], 0ull);
      ull bnv = atomicMax(&best_neg[i], 0ull);
      if (bpv != SENT_P && bnv != SENT_N) {
        unsigned pRaw = ~(unsigned)bpv;
        unsigned nRaw = (unsigned)bnv;
        int pi = pRaw < (unsigned)B ? (int)pRaw : 0;
        int nj = nRaw < (unsigned)B ? (int)nRaw : 0;
        float distp = __uint_as_float((unsigned)(bpv >> 32));
        float distn = __uint_as_float((unsigned)(bnv >> 32));
        float ri = rs[i];
        const float e = 1e-6f, de2 = (float)D * 1e-12f;
        float dp2 = distp * distp + 2.0f * e * (ri - rs[pi]) + de2;
        float dn2 = distn * distn + 2.0f * e * (ri - rs[nj]) + de2;
        float dp = sqrtf(fmaxf(dp2, 0.0f));
        float dn = sqrtf(fmaxf(dn2, 0.0f));
        per += fmaxf(dp - dn + 0.3f, 0.0f);
        v += 1;
      }
    }
    for (int off = 32; off; off >>= 1) {
      per += __shfl_down(per, off, 64);
      v   += __shfl_down(v, off, 64);
    }
    __shared__ float pps[4];
    __shared__ int pvs[4];
    if (lane == 0) { pps[wave] = per; pvs[wave] = v; }
    __syncthreads();
    if (tid == 0) {
      float t = pps[0] + pps[1] + pps[2] + pps[3];
      int cv = pvs[0] + pvs[1] + pvs[2] + pvs[3];
      out[0] = cv > 0 ? t / (float)cv : 0.0f;
    }
  }
}

// ---------------- launch -----------------------------------------------------
extern "C" void kernel_launch(void* const* d_in, const int* in_sizes, int n_in,
                              void* d_out, int out_size, void* d_ws, size_t ws_size,
                              hipStream_t stream) {
  const float* emb = (const float*)d_in[0];
  const int* labels = (const int*)d_in[1];
  float* out = (float*)d_out;
  char* ws = (char*)d_ws;

  const size_t off_embq = 0;
  const size_t off_sq   = off_embq + (size_t)B * D;       // 8 MiB
  const size_t off_rs   = off_sq + (size_t)B * 4;
  const size_t off_bp   = off_rs + (size_t)B * 4;
  const size_t off_bn   = off_bp + (size_t)B * 8;
  const size_t off_done = off_bn + (size_t)B * 8;

  unsigned char* embq = (unsigned char*)(ws + off_embq);
  float* sq   = (float*)(ws + off_sq);
  float* rs   = (float*)(ws + off_rs);
  ull* bp     = (ull*)(ws + off_bp);
  ull* bn     = (ull*)(ws + off_bn);
  int* done   = (int*)(ws + off_done);

  hipLaunchKernelGGL(k_convert_sq, dim3(B), dim3(256), 0, stream,
                     emb, embq, sq, rs, bp, bn, done);
  hipLaunchKernelGGL(k_gemm_select, dim3(1056), dim3(256), 0, stream,
                     embq, sq, labels, rs, bp, bn, done, out);
}

// Round 9
// 191.755 us; speedup vs baseline: 1.3324x; 1.0173x over previous
//
#include <hip/hip_runtime.h>
#include <stdint.h>

#define B 4096
#define D 2048
#define BK 128          // k-slab per K-step (fp8 elements; 128 B rows)
#define NITER (D / BK)  // 16
#define BM 64
#define BN 128

typedef unsigned long long ull;
typedef float f32x4 __attribute__((ext_vector_type(4)));
typedef long v2l __attribute__((ext_vector_type(2)));  // 16 B, 16-B aligned

#define SENT_P 0x00000000FFFFFFFFull  // dist=0.0, ~idx -> "no positive seen"
#define SENT_N (~0ull)                // +inf      -> "no negative seen"

// ---------------- async global->LDS (16B per lane, wave-uniform LDS base) ----
__device__ __forceinline__ void async_copy16(const unsigned char* g, unsigned char* l) {
  __builtin_amdgcn_global_load_lds(
      (const __attribute__((address_space(1))) unsigned int*)g,
      (__attribute__((address_space(3))) unsigned int*)l,
      16, 0, 0);
}

// ---------------- fp32 -> fp8 e4m3 (OCP, RNE) + norms + sentinel init -------
// embq is written in a k-PERMUTED layout (dot products are invariant under a
// uniform k-permutation of both operands). Within each 128 B K-step segment:
//   orig k = s*32 + qp*8 + b  (s=slab 0..3, qp=MFMA lane-group 0..3, b=0..7)
//   stored at pos = qp*32 + s*8 + b   ("q-major")
// so one 16 B chunk c = qp*2 + (s>>1) holds a lane-group's fragments for TWO
// consecutive slabs -> the GEMM reads it with a single ds_read_b128 at the
// conflict-free b128 bank floor.
__global__ void k_convert_sq(const float* __restrict__ emb,
                             unsigned char* __restrict__ embq,
                             float* __restrict__ sq,
                             float* __restrict__ rs,
                             ull* __restrict__ bp,
                             ull* __restrict__ bn,
                             int* __restrict__ gemm_done) {
  const int row = blockIdx.x, t = threadIdx.x;
  const float4* src = (const float4*)(emb + (size_t)row * D);
  float4 v0 = src[2 * t], v1 = src[2 * t + 1];
  float s = v0.x * v0.x + v0.y * v0.y + v0.z * v0.z + v0.w * v0.w
          + v1.x * v1.x + v1.y * v1.y + v1.z * v1.z + v1.w * v1.w;
  float sm = v0.x + v0.y + v0.z + v0.w + v1.x + v1.y + v1.z + v1.w;

  unsigned w0 = __builtin_amdgcn_cvt_pk_fp8_f32(v0.x, v0.y, 0, false);
  w0 = __builtin_amdgcn_cvt_pk_fp8_f32(v0.z, v0.w, w0, true);
  unsigned w1 = __builtin_amdgcn_cvt_pk_fp8_f32(v1.x, v1.y, 0, false);
  w1 = __builtin_amdgcn_cvt_pk_fp8_f32(v1.z, v1.w, w1, true);
  uint2 o; o.x = w0; o.y = w1;
  // thread t holds orig k in [8t, 8t+8): kb = t>>4, s = (t>>2)&3, qp = t&3
  const int pos = ((t >> 4) << 7) | ((t & 3) << 5) | (((t >> 2) & 3) << 3);
  *(uint2*)(embq + (size_t)row * D + pos) = o;

  for (int off = 32; off; off >>= 1) {
    s  += __shfl_down(s, off, 64);
    sm += __shfl_down(sm, off, 64);
  }
  __shared__ float ps[4], pm[4];
  int lane = t & 63, wave = t >> 6;
  if (lane == 0) { ps[wave] = s; pm[wave] = sm; }
  __syncthreads();
  if (t == 0) {
    sq[row] = ps[0] + ps[1] + ps[2] + ps[3];
    rs[row] = pm[0] + pm[1] + pm[2] + pm[3];
    bp[row] = SENT_P;
    bn[row] = SENT_N;
    if (row == 0) *gemm_done = 0;
  }
}

// ---------------- fused symmetric fp8 GEMM + selection + tail loss ----------
// R3 proven GEMM structure EXACTLY (64x128 tiles over the strict upper
// triangle, 1056 blocks, 4 waves as 2x2, single-buffered 24 KB LDS, 2-barrier
// K-loop; all 1056 blocks co-resident at 6 blocks/CU so inter-block TLP hides
// the staging drain). Fused tail loss via done-counter (R8: saved ~17 us of
// kernel-boundary overhead). R8's regression root-caused: the tail read
// best_pos/best_neg with 8192 device-scope atomic RMWs-with-return from one
// block (~30 cyc serialized each ~= 90 us idle GPU). Fix: device-scope atomic
// LOADS (__hip_atomic_load relaxed/agent = flagged loads, bypass L1/L2 but
// pipeline at full load throughput). Coherence-safe: all writes to best_* in
// this kernel are device-scope atomics at the coherence point and no block
// plain-loads those lines, so no stale cached copies exist anywhere.
__launch_bounds__(256, 4)
__global__ void k_gemm_select(const unsigned char* __restrict__ embq,
                              const float* __restrict__ sq,
                              const int* __restrict__ labels,
                              const float* __restrict__ rs,
                              ull* __restrict__ best_pos,
                              ull* __restrict__ best_neg,
                              int* __restrict__ gemm_done,
                              float* __restrict__ out) {
  __shared__ __align__(16) unsigned char ldsA[BM * BK];  // 8 KB
  __shared__ __align__(16) unsigned char ldsB[BN * BK];  // 16 KB

  // linear bid -> (by in [0,64), bx in [0,32)) with bx*128+127 > by*64
  int rem = blockIdx.x, p = 0;
  while (rem >= 2 * (32 - p)) { rem -= 2 * (32 - p); ++p; }
  int by = 2 * p;
  int c = 32 - p;
  if (rem >= c) { by += 1; rem -= c; }
  const int bx = p + rem;

  const int tid  = threadIdx.x;
  const int lane = tid & 63;
  const int wave = tid >> 6;
  const int wm = wave >> 1, wn = wave & 1;
  const int q = lane >> 4, m15 = lane & 15;
  const int ibase = by * BM, jbase = bx * BN;

  // b128 fragment read offsets for slab-pair sh (slabs 2sh, 2sh+1), group g:
  //   row = wbase + g*16 + m15 ; chunk = q*2 + sh ; slot = chunk ^ (row&7)
  //   byte = row*128 + slot*16   (16-B aligned; [0,8)=slab 2sh, [8,16)=2sh+1)
  int aoff[2][2], boff[2][4];
#pragma unroll
  for (int sh = 0; sh < 2; ++sh) {
#pragma unroll
    for (int g = 0; g < 2; ++g) {
      int ra = wm * 32 + g * 16 + m15;
      aoff[sh][g] = ra * BK + (((q * 2 + sh) ^ (ra & 7)) * 16);
    }
#pragma unroll
    for (int g = 0; g < 4; ++g) {
      int rb = wn * 64 + g * 16 + m15;
      boff[sh][g] = rb * BK + (((q * 2 + sh) ^ (rb & 7)) * 16);
    }
  }

  // staging: 6 issues/wave per K-step (2 A + 4 B), 8 rows x 1 KB per issue.
  // LDS dest linear (base + lane*16); global source pre-swizzled so LDS slot
  // `slot` holds global chunk slot^(row&7)  (XOR involution matches reads).
  const int srow = lane >> 3;  // row within 8-row staging group
  const int slot = lane & 7;   // 16B slot within 128B row
  size_t agoff[2], bgoff[4];
  int lasta[2], lastb[4];
#pragma unroll
  for (int pp = 0; pp < 2; ++pp) {
    int r0  = wave * 16 + pp * 8;  // wave-uniform
    int row = r0 + srow;
    agoff[pp] = (size_t)(ibase + row) * D + (slot ^ (row & 7)) * 16;
    lasta[pp] = r0 * BK;
  }
#pragma unroll
  for (int pp = 0; pp < 4; ++pp) {
    int r0  = wave * 32 + pp * 8;  // wave-uniform
    int row = r0 + srow;
    bgoff[pp] = (size_t)(jbase + row) * D + (slot ^ (row & 7)) * 16;
    lastb[pp] = r0 * BK;
  }

  f32x4 acc[2][4];
  const f32x4 z = {0.f, 0.f, 0.f, 0.f};
#pragma unroll
  for (int a = 0; a < 2; ++a)
#pragma unroll
    for (int b = 0; b < 4; ++b) acc[a][b] = z;

  for (int kb = 0; kb < D; kb += BK) {
    __syncthreads();
#pragma unroll
    for (int pp = 0; pp < 2; ++pp)
      async_copy16(embq + agoff[pp] + kb, &ldsA[lasta[pp]]);
#pragma unroll
    for (int pp = 0; pp < 4; ++pp)
      async_copy16(embq + bgoff[pp] + kb, &ldsB[lastb[pp]]);
    __syncthreads();  // compiler emits vmcnt(0) drain before barrier

#pragma unroll
    for (int sh = 0; sh < 2; ++sh) {
      v2l af[2], bf[4];
#pragma unroll
      for (int g = 0; g < 2; ++g) af[g] = *(const v2l*)&ldsA[aoff[sh][g]];
#pragma unroll
      for (int g = 0; g < 4; ++g) bf[g] = *(const v2l*)&ldsB[boff[sh][g]];
#pragma unroll
      for (int mi = 0; mi < 2; ++mi)
#pragma unroll
        for (int ni = 0; ni < 4; ++ni)
          acc[mi][ni] = __builtin_amdgcn_mfma_f32_16x16x32_fp8_fp8(
              af[mi][0], bf[ni][0], acc[mi][ni], 0, 0, 0);
#pragma unroll
      for (int mi = 0; mi < 2; ++mi)
#pragma unroll
        for (int ni = 0; ni < 4; ++ni)
          acc[mi][ni] = __builtin_amdgcn_mfma_f32_16x16x32_fp8_fp8(
              af[mi][1], bf[ni][1], acc[mi][ni], 0, 0, 0);
    }
  }

  // ---- epilogue ----
  float sqj[4];
  int labj[4];
#pragma unroll
  for (int ni = 0; ni < 4; ++ni) {
    int jj = jbase + wn * 64 + ni * 16 + m15;
    sqj[ni] = sq[jj];
    labj[ni] = labels[jj];
  }

  ull colBp[4], colBn[4];
#pragma unroll
  for (int ni = 0; ni < 4; ++ni) { colBp[ni] = SENT_P; colBn[ni] = SENT_N; }

#pragma unroll
  for (int mi = 0; mi < 2; ++mi) {
#pragma unroll
    for (int r = 0; r < 4; ++r) {
      const int i = ibase + wm * 32 + mi * 16 + q * 4 + r;  // C/D row=(lane>>4)*4+r
      const float si = sq[i];
      const int li = labels[i];
      ull bp = SENT_P;
      ull bn = SENT_N;
#pragma unroll
      for (int ni = 0; ni < 4; ++ni) {
        int jj = jbase + wn * 64 + ni * 16 + m15;  // C/D col=lane&15
        if (jj > i) {                              // strict upper triangle only
          float dot = acc[mi][ni][r];
          float d2 = si + sqj[ni] - 2.0f * dot;
          float dist = sqrtf(fmaxf(d2, 0.0f));
          ull pv = ((ull)__float_as_uint(dist)) << 32;
          if (labj[ni] == li) {
            ull cr = pv | (unsigned)(~jj);  // max -> smallest idx wins ties
            bp = bp > cr ? bp : cr;
            ull cc = pv | (unsigned)(~i);
            colBp[ni] = colBp[ni] > cc ? colBp[ni] : cc;
          } else {
            ull cr = pv | (unsigned)jj;     // min -> smallest idx wins ties
            bn = bn < cr ? bn : cr;
            ull cc = pv | (unsigned)i;
            colBn[ni] = colBn[ni] < cc ? colBn[ni] : cc;
          }
        }
      }
      // row-i reduction across the 16 column lanes (m15 bits)
#pragma unroll
      for (int off = 1; off <= 8; off <<= 1) {
        ull op = __shfl_xor(bp, off, 64);
        ull on = __shfl_xor(bn, off, 64);
        bp = bp > op ? bp : op;
        bn = bn < on ? bn : on;
      }
      if (m15 == 0) {
        if (bp != SENT_P) atomicMax(&best_pos[i], bp);
        if (bn != SENT_N) atomicMin(&best_neg[i], bn);
      }
    }
  }

  // col-j reduction across the 4 q lane-groups
#pragma unroll
  for (int ni = 0; ni < 4; ++ni) {
    ull cp = colBp[ni], cn = colBn[ni];
#pragma unroll
    for (int off = 16; off <= 32; off <<= 1) {
      ull op = __shfl_xor(cp, off, 64);
      ull on = __shfl_xor(cn, off, 64);
      cp = cp > op ? cp : op;
      cn = cn < on ? cn : on;
    }
    if (q == 0) {
      int j = jbase + wn * 64 + ni * 16 + m15;
      if (cp != SENT_P) atomicMax(&best_pos[j], cp);
      if (cn != SENT_N) atomicMin(&best_neg[j], cn);
    }
  }

  // ---- fused tail loss: last block to finish computes the final mean ------
  __threadfence();           // make this block's atomics device-visible
  __syncthreads();           // all waves' atomics issued before the count
  __shared__ int sLast;
  if (tid == 0) sLast = (atomicAdd(gemm_done, 1) == (int)gridDim.x - 1);
  __syncthreads();
  if (sLast) {
    float per = 0.0f;
    int v = 0;
#pragma unroll 4
    for (int i = tid; i < B; i += 256) {
      // device-scope atomic LOADS: bypass L1/L2 (read coherence point),
      // pipeline at load throughput — NOT serialized RMWs (R8's 90 us bug)
      ull bpv = __hip_atomic_load(&best_pos[i], __ATOMIC_RELAXED,
                                  __HIP_MEMORY_SCOPE_AGENT);
      ull bnv = __hip_atomic_load(&best_neg[i], __ATOMIC_RELAXED,
                                  __HIP_MEMORY_SCOPE_AGENT);
      if (bpv != SENT_P && bnv != SENT_N) {
        unsigned pRaw = ~(unsigned)bpv;
        unsigned nRaw = (unsigned)bnv;
        int pi = pRaw < (unsigned)B ? (int)pRaw : 0;
        int nj = nRaw < (unsigned)B ? (int)nRaw : 0;
        float distp = __uint_as_float((unsigned)(bpv >> 32));
        float distn = __uint_as_float((unsigned)(bnv >> 32));
        float ri = rs[i];
        const float e = 1e-6f, de2 = (float)D * 1e-12f;
        float dp2 = distp * distp + 2.0f * e * (ri - rs[pi]) + de2;
        float dn2 = distn * distn + 2.0f * e * (ri - rs[nj]) + de2;
        float dp = sqrtf(fmaxf(dp2, 0.0f));
        float dn = sqrtf(fmaxf(dn2, 0.0f));
        per += fmaxf(dp - dn + 0.3f, 0.0f);
        v += 1;
      }
    }
    for (int off = 32; off; off >>= 1) {
      per += __shfl_down(per, off, 64);
      v   += __shfl_down(v, off, 64);
    }
    __shared__ float pps[4];
    __shared__ int pvs[4];
    if (lane == 0) { pps[wave] = per; pvs[wave] = v; }
    __syncthreads();
    if (tid == 0) {
      float t = pps[0] + pps[1] + pps[2] + pps[3];
      int cv = pvs[0] + pvs[1] + pvs[2] + pvs[3];
      out[0] = cv > 0 ? t / (float)cv : 0.0f;
    }
  }
}

// ---------------- launch -----------------------------------------------------
extern "C" void kernel_launch(void* const* d_in, const int* in_sizes, int n_in,
                              void* d_out, int out_size, void* d_ws, size_t ws_size,
                              hipStream_t stream) {
  const float* emb = (const float*)d_in[0];
  const int* labels = (const int*)d_in[1];
  float* out = (float*)d_out;
  char* ws = (char*)d_ws;

  const size_t off_embq = 0;
  const size_t off_sq   = off_embq + (size_t)B * D;       // 8 MiB
  const size_t off_rs   = off_sq + (size_t)B * 4;
  const size_t off_bp   = off_rs + (size_t)B * 4;
  const size_t off_bn   = off_bp + (size_t)B * 8;
  const size_t off_done = off_bn + (size_t)B * 8;

  unsigned char* embq = (unsigned char*)(ws + off_embq);
  float* sq   = (float*)(ws + off_sq);
  float* rs   = (float*)(ws + off_rs);
  ull* bp     = (ull*)(ws + off_bp);
  ull* bn     = (ull*)(ws + off_bn);
  int* done   = (int*)(ws + off_done);

  hipLaunchKernelGGL(k_convert_sq, dim3(B), dim3(256), 0, stream,
                     emb, embq, sq, rs, bp, bn, done);
  hipLaunchKernelGGL(k_gemm_select, dim3(1056), dim3(256), 0, stream,
                     embq, sq, labels, rs, bp, bn, done, out);
}

// Round 10
// 132.467 us; speedup vs baseline: 1.9287x; 1.4476x over previous
//
#include <hip/hip_runtime.h>
#include <stdint.h>

#define B 4096
#define D 2048
#define BK 128          // k-slab per K-step (fp8 elements; 128 B rows)
#define NITER (D / BK)  // 16
#define BM 64
#define BN 128
#define GRID 1056
#define NTAIL 16        // tail-parallel blocks; NTAIL*256 == B

typedef unsigned long long ull;
typedef float f32x4 __attribute__((ext_vector_type(4)));
typedef long v2l __attribute__((ext_vector_type(2)));  // 16 B, 16-B aligned

#define SENT_P 0x00000000FFFFFFFFull  // dist=0.0, ~idx -> "no positive seen"
#define SENT_N (~0ull)                // +inf      -> "no negative seen"

// ---------------- async global->LDS (16B per lane, wave-uniform LDS base) ----
__device__ __forceinline__ void async_copy16(const unsigned char* g, unsigned char* l) {
  __builtin_amdgcn_global_load_lds(
      (const __attribute__((address_space(1))) unsigned int*)g,
      (__attribute__((address_space(3))) unsigned int*)l,
      16, 0, 0);
}

// ---------------- fp32 -> fp8 e4m3 (OCP, RNE) + norms + sentinel init -------
// embq is written in a k-PERMUTED layout (dot products are invariant under a
// uniform k-permutation of both operands). Within each 128 B K-step segment:
//   orig k = s*32 + qp*8 + b  (s=slab 0..3, qp=MFMA lane-group 0..3, b=0..7)
//   stored at pos = qp*32 + s*8 + b   ("q-major")
// so one 16 B chunk c = qp*2 + (s>>1) holds a lane-group's fragments for TWO
// consecutive slabs -> the GEMM reads it with a single ds_read_b128 at the
// conflict-free b128 bank floor.
__global__ void k_convert_sq(const float* __restrict__ emb,
                             unsigned char* __restrict__ embq,
                             float* __restrict__ sq,
                             float* __restrict__ rs,
                             ull* __restrict__ bp,
                             ull* __restrict__ bn,
                             int* __restrict__ gemm_done,
                             float* __restrict__ red_sum,
                             int* __restrict__ red_cnt,
                             int* __restrict__ done2) {
  const int row = blockIdx.x, t = threadIdx.x;
  const float4* src = (const float4*)(emb + (size_t)row * D);
  float4 v0 = src[2 * t], v1 = src[2 * t + 1];
  float s = v0.x * v0.x + v0.y * v0.y + v0.z * v0.z + v0.w * v0.w
          + v1.x * v1.x + v1.y * v1.y + v1.z * v1.z + v1.w * v1.w;
  float sm = v0.x + v0.y + v0.z + v0.w + v1.x + v1.y + v1.z + v1.w;

  unsigned w0 = __builtin_amdgcn_cvt_pk_fp8_f32(v0.x, v0.y, 0, false);
  w0 = __builtin_amdgcn_cvt_pk_fp8_f32(v0.z, v0.w, w0, true);
  unsigned w1 = __builtin_amdgcn_cvt_pk_fp8_f32(v1.x, v1.y, 0, false);
  w1 = __builtin_amdgcn_cvt_pk_fp8_f32(v1.z, v1.w, w1, true);
  uint2 o; o.x = w0; o.y = w1;
  // thread t holds orig k in [8t, 8t+8): kb = t>>4, s = (t>>2)&3, qp = t&3
  const int pos = ((t >> 4) << 7) | ((t & 3) << 5) | (((t >> 2) & 3) << 3);
  *(uint2*)(embq + (size_t)row * D + pos) = o;

  for (int off = 32; off; off >>= 1) {
    s  += __shfl_down(s, off, 64);
    sm += __shfl_down(sm, off, 64);
  }
  __shared__ float ps[4], pm[4];
  int lane = t & 63, wave = t >> 6;
  if (lane == 0) { ps[wave] = s; pm[wave] = sm; }
  __syncthreads();
  if (t == 0) {
    sq[row] = ps[0] + ps[1] + ps[2] + ps[3];
    rs[row] = pm[0] + pm[1] + pm[2] + pm[3];
    bp[row] = SENT_P;
    bn[row] = SENT_N;
    if (row == 0) {
      *gemm_done = 0; *red_sum = 0.0f; *red_cnt = 0; *done2 = 0;
    }
  }
}

// ---------------- fused symmetric fp8 GEMM + selection + parallel tail ------
// R3 proven GEMM structure EXACTLY (64x128 tiles over the strict upper
// triangle, 1056 blocks, 4 waves as 2x2, single-buffered 24 KB LDS, 2-barrier
// K-loop; all 1056 blocks co-resident at 6 blocks/CU). Tail changes vs R9:
//  (a) NO __threadfence — on gfx950 it emits L2 writeback/invalidate cache
//      maintenance; 1056 of them during the run poison embq L2 reuse for all
//      in-flight blocks. It is redundant here: __syncthreads() already drains
//      vmcnt(0) in every wave (m97 asm), and best_* writes are device-scope
//      atomics executing AT the coherence point — vmcnt retirement == global
//      visibility. The done-counter add after the barrier is therefore a
//      correct release.
//  (b) tail parallelized across the last NTAIL=16 blocks (1 anchor/thread,
//      no loop); they spin until done==GRID (deadlock-free: grid fully
//      co-resident), partial-sum via device atomics, and the 16th writes out.
__launch_bounds__(256, 4)
__global__ void k_gemm_select(const unsigned char* __restrict__ embq,
                              const float* __restrict__ sq,
                              const int* __restrict__ labels,
                              const float* __restrict__ rs,
                              ull* __restrict__ best_pos,
                              ull* __restrict__ best_neg,
                              int* __restrict__ gemm_done,
                              float* __restrict__ red_sum,
                              int* __restrict__ red_cnt,
                              int* __restrict__ done2,
                              float* __restrict__ out) {
  __shared__ __align__(16) unsigned char ldsA[BM * BK];  // 8 KB
  __shared__ __align__(16) unsigned char ldsB[BN * BK];  // 16 KB

  // linear bid -> (by in [0,64), bx in [0,32)) with bx*128+127 > by*64
  int rem = blockIdx.x, p = 0;
  while (rem >= 2 * (32 - p)) { rem -= 2 * (32 - p); ++p; }
  int by = 2 * p;
  int c = 32 - p;
  if (rem >= c) { by += 1; rem -= c; }
  const int bx = p + rem;

  const int tid  = threadIdx.x;
  const int lane = tid & 63;
  const int wave = tid >> 6;
  const int wm = wave >> 1, wn = wave & 1;
  const int q = lane >> 4, m15 = lane & 15;
  const int ibase = by * BM, jbase = bx * BN;

  // b128 fragment read offsets for slab-pair sh (slabs 2sh, 2sh+1), group g:
  //   row = wbase + g*16 + m15 ; chunk = q*2 + sh ; slot = chunk ^ (row&7)
  //   byte = row*128 + slot*16   (16-B aligned; [0,8)=slab 2sh, [8,16)=2sh+1)
  int aoff[2][2], boff[2][4];
#pragma unroll
  for (int sh = 0; sh < 2; ++sh) {
#pragma unroll
    for (int g = 0; g < 2; ++g) {
      int ra = wm * 32 + g * 16 + m15;
      aoff[sh][g] = ra * BK + (((q * 2 + sh) ^ (ra & 7)) * 16);
    }
#pragma unroll
    for (int g = 0; g < 4; ++g) {
      int rb = wn * 64 + g * 16 + m15;
      boff[sh][g] = rb * BK + (((q * 2 + sh) ^ (rb & 7)) * 16);
    }
  }

  // staging: 6 issues/wave per K-step (2 A + 4 B), 8 rows x 1 KB per issue.
  // LDS dest linear (base + lane*16); global source pre-swizzled so LDS slot
  // `slot` holds global chunk slot^(row&7)  (XOR involution matches reads).
  const int srow = lane >> 3;  // row within 8-row staging group
  const int slot = lane & 7;   // 16B slot within 128B row
  size_t agoff[2], bgoff[4];
  int lasta[2], lastb[4];
#pragma unroll
  for (int pp = 0; pp < 2; ++pp) {
    int r0  = wave * 16 + pp * 8;  // wave-uniform
    int row = r0 + srow;
    agoff[pp] = (size_t)(ibase + row) * D + (slot ^ (row & 7)) * 16;
    lasta[pp] = r0 * BK;
  }
#pragma unroll
  for (int pp = 0; pp < 4; ++pp) {
    int r0  = wave * 32 + pp * 8;  // wave-uniform
    int row = r0 + srow;
    bgoff[pp] = (size_t)(jbase + row) * D + (slot ^ (row & 7)) * 16;
    lastb[pp] = r0 * BK;
  }

  f32x4 acc[2][4];
  const f32x4 z = {0.f, 0.f, 0.f, 0.f};
#pragma unroll
  for (int a = 0; a < 2; ++a)
#pragma unroll
    for (int b = 0; b < 4; ++b) acc[a][b] = z;

  for (int kb = 0; kb < D; kb += BK) {
    __syncthreads();
#pragma unroll
    for (int pp = 0; pp < 2; ++pp)
      async_copy16(embq + agoff[pp] + kb, &ldsA[lasta[pp]]);
#pragma unroll
    for (int pp = 0; pp < 4; ++pp)
      async_copy16(embq + bgoff[pp] + kb, &ldsB[lastb[pp]]);
    __syncthreads();  // compiler emits vmcnt(0) drain before barrier

#pragma unroll
    for (int sh = 0; sh < 2; ++sh) {
      v2l af[2], bf[4];
#pragma unroll
      for (int g = 0; g < 2; ++g) af[g] = *(const v2l*)&ldsA[aoff[sh][g]];
#pragma unroll
      for (int g = 0; g < 4; ++g) bf[g] = *(const v2l*)&ldsB[boff[sh][g]];
#pragma unroll
      for (int mi = 0; mi < 2; ++mi)
#pragma unroll
        for (int ni = 0; ni < 4; ++ni)
          acc[mi][ni] = __builtin_amdgcn_mfma_f32_16x16x32_fp8_fp8(
              af[mi][0], bf[ni][0], acc[mi][ni], 0, 0, 0);
#pragma unroll
      for (int mi = 0; mi < 2; ++mi)
#pragma unroll
        for (int ni = 0; ni < 4; ++ni)
          acc[mi][ni] = __builtin_amdgcn_mfma_f32_16x16x32_fp8_fp8(
              af[mi][1], bf[ni][1], acc[mi][ni], 0, 0, 0);
    }
  }

  // ---- epilogue ----
  float sqj[4];
  int labj[4];
#pragma unroll
  for (int ni = 0; ni < 4; ++ni) {
    int jj = jbase + wn * 64 + ni * 16 + m15;
    sqj[ni] = sq[jj];
    labj[ni] = labels[jj];
  }

  ull colBp[4], colBn[4];
#pragma unroll
  for (int ni = 0; ni < 4; ++ni) { colBp[ni] = SENT_P; colBn[ni] = SENT_N; }

#pragma unroll
  for (int mi = 0; mi < 2; ++mi) {
#pragma unroll
    for (int r = 0; r < 4; ++r) {
      const int i = ibase + wm * 32 + mi * 16 + q * 4 + r;  // C/D row=(lane>>4)*4+r
      const float si = sq[i];
      const int li = labels[i];
      ull bp = SENT_P;
      ull bn = SENT_N;
#pragma unroll
      for (int ni = 0; ni < 4; ++ni) {
        int jj = jbase + wn * 64 + ni * 16 + m15;  // C/D col=lane&15
        if (jj > i) {                              // strict upper triangle only
          float dot = acc[mi][ni][r];
          float d2 = si + sqj[ni] - 2.0f * dot;
          float dist = sqrtf(fmaxf(d2, 0.0f));
          ull pv = ((ull)__float_as_uint(dist)) << 32;
          if (labj[ni] == li) {
            ull cr = pv | (unsigned)(~jj);  // max -> smallest idx wins ties
            bp = bp > cr ? bp : cr;
            ull cc = pv | (unsigned)(~i);
            colBp[ni] = colBp[ni] > cc ? colBp[ni] : cc;
          } else {
            ull cr = pv | (unsigned)jj;     // min -> smallest idx wins ties
            bn = bn < cr ? bn : cr;
            ull cc = pv | (unsigned)i;
            colBn[ni] = colBn[ni] < cc ? colBn[ni] : cc;
          }
        }
      }
      // row-i reduction across the 16 column lanes (m15 bits)
#pragma unroll
      for (int off = 1; off <= 8; off <<= 1) {
        ull op = __shfl_xor(bp, off, 64);
        ull on = __shfl_xor(bn, off, 64);
        bp = bp > op ? bp : op;
        bn = bn < on ? bn : on;
      }
      if (m15 == 0) {
        if (bp != SENT_P) atomicMax(&best_pos[i], bp);
        if (bn != SENT_N) atomicMin(&best_neg[i], bn);
      }
    }
  }

  // col-j reduction across the 4 q lane-groups
#pragma unroll
  for (int ni = 0; ni < 4; ++ni) {
    ull cp = colBp[ni], cn = colBn[ni];
#pragma unroll
    for (int off = 16; off <= 32; off <<= 1) {
      ull op = __shfl_xor(cp, off, 64);
      ull on = __shfl_xor(cn, off, 64);
      cp = cp > op ? cp : op;
      cn = cn < on ? cn : on;
    }
    if (q == 0) {
      int j = jbase + wn * 64 + ni * 16 + m15;
      if (cp != SENT_P) atomicMax(&best_pos[j], cp);
      if (cn != SENT_N) atomicMin(&best_neg[j], cn);
    }
  }

  // ---- parallel tail loss: last NTAIL blocks, 1 anchor per thread ---------
  // __syncthreads drains vmcnt(0) in every wave => all this block's epilogue
  // atomics have executed at the coherence point (release). No threadfence.
  __syncthreads();
  __shared__ int sIdx;
  if (tid == 0)
    sIdx = atomicAdd(gemm_done, 1) - (GRID - NTAIL);
  __syncthreads();
  const int idx = sIdx;
  if (idx >= 0) {
    if (tid == 0) {  // wait until ALL blocks' epilogue atomics are in
      while (__hip_atomic_load(gemm_done, __ATOMIC_RELAXED,
                               __HIP_MEMORY_SCOPE_AGENT) < GRID)
        __builtin_amdgcn_s_sleep(2);
    }
    __syncthreads();

    const int i = idx * 256 + tid;   // NTAIL*256 == B: one anchor per thread
    float per = 0.0f;
    int v = 0;
    ull bpv = __hip_atomic_load(&best_pos[i], __ATOMIC_RELAXED,
                                __HIP_MEMORY_SCOPE_AGENT);
    ull bnv = __hip_atomic_load(&best_neg[i], __ATOMIC_RELAXED,
                                __HIP_MEMORY_SCOPE_AGENT);
    if (bpv != SENT_P && bnv != SENT_N) {
      unsigned pRaw = ~(unsigned)bpv;
      unsigned nRaw = (unsigned)bnv;
      int pi = pRaw < (unsigned)B ? (int)pRaw : 0;
      int nj = nRaw < (unsigned)B ? (int)nRaw : 0;
      float distp = __uint_as_float((unsigned)(bpv >> 32));
      float distn = __uint_as_float((unsigned)(bnv >> 32));
      float ri = rs[i];
      const float e = 1e-6f, de2 = (float)D * 1e-12f;
      float dp2 = distp * distp + 2.0f * e * (ri - rs[pi]) + de2;
      float dn2 = distn * distn + 2.0f * e * (ri - rs[nj]) + de2;
      float dp = sqrtf(fmaxf(dp2, 0.0f));
      float dn = sqrtf(fmaxf(dn2, 0.0f));
      per = fmaxf(dp - dn + 0.3f, 0.0f);
      v = 1;
    }
    for (int off = 32; off; off >>= 1) {
      per += __shfl_down(per, off, 64);
      v   += __shfl_down(v, off, 64);
    }
    __shared__ float pps[4];
    __shared__ int pvs[4];
    if (lane == 0) { pps[wave] = per; pvs[wave] = v; }
    __syncthreads();
    if (tid == 0) {
      atomicAdd(red_sum, pps[0] + pps[1] + pps[2] + pps[3]);
      atomicAdd(red_cnt, pvs[0] + pvs[1] + pvs[2] + pvs[3]);
      asm volatile("s_waitcnt vmcnt(0)" ::: "memory");  // release partials
      int o2 = atomicAdd(done2, 1);
      if (o2 == NTAIL - 1) {
        float s = __hip_atomic_load(red_sum, __ATOMIC_RELAXED,
                                    __HIP_MEMORY_SCOPE_AGENT);
        int cc = __hip_atomic_load(red_cnt, __ATOMIC_RELAXED,
                                   __HIP_MEMORY_SCOPE_AGENT);
        out[0] = cc > 0 ? s / (float)cc : 0.0f;
      }
    }
  }
}

// ---------------- launch -----------------------------------------------------
extern "C" void kernel_launch(void* const* d_in, const int* in_sizes, int n_in,
                              void* d_out, int out_size, void* d_ws, size_t ws_size,
                              hipStream_t stream) {
  const float* emb = (const float*)d_in[0];
  const int* labels = (const int*)d_in[1];
  float* out = (float*)d_out;
  char* ws = (char*)d_ws;

  const size_t off_embq = 0;
  const size_t off_sq   = off_embq + (size_t)B * D;       // 8 MiB
  const size_t off_rs   = off_sq + (size_t)B * 4;
  const size_t off_bp   = off_rs + (size_t)B * 4;
  const size_t off_bn   = off_bp + (size_t)B * 8;
  const size_t off_ctl  = off_bn + (size_t)B * 8;

  unsigned char* embq = (unsigned char*)(ws + off_embq);
  float* sq   = (float*)(ws + off_sq);
  float* rs   = (float*)(ws + off_rs);
  ull* bp     = (ull*)(ws + off_bp);
  ull* bn     = (ull*)(ws + off_bn);
  int* done   = (int*)(ws + off_ctl);
  float* red_sum = (float*)(ws + off_ctl + 8);
  int* red_cnt   = (int*)(ws + off_ctl + 16);
  int* done2     = (int*)(ws + off_ctl + 24);

  hipLaunchKernelGGL(k_convert_sq, dim3(B), dim3(256), 0, stream,
                     emb, embq, sq, rs, bp, bn, done, red_sum, red_cnt, done2);
  hipLaunchKernelGGL(k_gemm_select, dim3(GRID), dim3(256), 0, stream,
                     embq, sq, labels, rs, bp, bn, done, red_sum, red_cnt,
                     done2, out);
}

// Round 11
// 120.381 us; speedup vs baseline: 2.1224x; 1.1004x over previous
//
#include <hip/hip_runtime.h>
#include <stdint.h>

#define B 4096
#define D 2048
#define BK 128          // k-slab per K-step (fp8 elements; 128 B rows)
#define NITER (D / BK)  // 16
#define BM 64
#define BN 128

typedef unsigned long long ull;
typedef float f32x4 __attribute__((ext_vector_type(4)));
typedef long v2l __attribute__((ext_vector_type(2)));  // 16 B, 16-B aligned

#define SENT_P 0x00000000FFFFFFFFull  // dist=0.0, ~idx -> "no positive seen"
#define SENT_N (~0ull)                // +inf      -> "no negative seen"

// ---------------- async global->LDS (16B per lane, wave-uniform LDS base) ----
__device__ __forceinline__ void async_copy16(const unsigned char* g, unsigned char* l) {
  __builtin_amdgcn_global_load_lds(
      (const __attribute__((address_space(1))) unsigned int*)g,
      (__attribute__((address_space(3))) unsigned int*)l,
      16, 0, 0);
}

// ---------------- fp32 -> fp8 e4m3 (OCP, RNE) + norms + sentinel init -------
// embq is written in a k-PERMUTED layout (dot products are invariant under a
// uniform k-permutation of both operands). Within each 128 B K-step segment:
//   orig k = s*32 + qp*8 + b  (s=slab 0..3, qp=MFMA lane-group 0..3, b=0..7)
//   stored at pos = qp*32 + s*8 + b   ("q-major")
// so one 16 B chunk c = qp*2 + (s>>1) holds a lane-group's fragments for TWO
// consecutive slabs -> the GEMM reads it with a single ds_read_b128 whose
// 64-lane bank pattern covers all 32 banks (free 2-way) instead of the
// irreducible 2x 16-bank conflict of 8 B reads.
__global__ void k_convert_sq(const float* __restrict__ emb,
                             unsigned char* __restrict__ embq,
                             float* __restrict__ sq,
                             float* __restrict__ rs,
                             ull* __restrict__ bp,
                             ull* __restrict__ bn) {
  const int row = blockIdx.x, t = threadIdx.x;
  const float4* src = (const float4*)(emb + (size_t)row * D);
  float4 v0 = src[2 * t], v1 = src[2 * t + 1];
  float s = v0.x * v0.x + v0.y * v0.y + v0.z * v0.z + v0.w * v0.w
          + v1.x * v1.x + v1.y * v1.y + v1.z * v1.z + v1.w * v1.w;
  float sm = v0.x + v0.y + v0.z + v0.w + v1.x + v1.y + v1.z + v1.w;

  unsigned w0 = __builtin_amdgcn_cvt_pk_fp8_f32(v0.x, v0.y, 0, false);
  w0 = __builtin_amdgcn_cvt_pk_fp8_f32(v0.z, v0.w, w0, true);
  unsigned w1 = __builtin_amdgcn_cvt_pk_fp8_f32(v1.x, v1.y, 0, false);
  w1 = __builtin_amdgcn_cvt_pk_fp8_f32(v1.z, v1.w, w1, true);
  uint2 o; o.x = w0; o.y = w1;
  // thread t holds orig k in [8t, 8t+8): kb = t>>4, s = (t>>2)&3, qp = t&3
  const int pos = ((t >> 4) << 7) | ((t & 3) << 5) | (((t >> 2) & 3) << 3);
  *(uint2*)(embq + (size_t)row * D + pos) = o;

  for (int off = 32; off; off >>= 1) {
    s  += __shfl_down(s, off, 64);
    sm += __shfl_down(sm, off, 64);
  }
  __shared__ float ps[4], pm[4];
  int lane = t & 63, wave = t >> 6;
  if (lane == 0) { ps[wave] = s; pm[wave] = sm; }
  __syncthreads();
  if (t == 0) {
    sq[row] = ps[0] + ps[1] + ps[2] + ps[3];
    rs[row] = pm[0] + pm[1] + pm[2] + pm[3];
    bp[row] = SENT_P;
    bn[row] = SENT_N;
  }
}

// ---------------- fused symmetric fp8 GEMM + hard pos/neg selection ---------
// Measured session optimum (R3, 47 us). 64x128 tiles over the strict upper
// triangle (1056 blocks, sequential triangular decode), 4 waves as 2x2,
// single-buffered 24 KB LDS -> 6 blocks/CU co-resident; the 2-barrier K-loop
// relies on inter-block TLP to hide the staging drain. Refuted alternatives
// (all measured slower): deep/minimal counted-vmcnt pipelines (R1/R2/R5),
// 128x128 and 2-wave tiles (R1/R4), XCD swizzle (R2, FETCH +27%), scaled
// 16x16x128 MFMA (R6/R7, compiler scratch), in-kernel fused tail (R8-R10,
// sync cost > kernel boundary). q-major b128 fragment reads run at the LDS
// b128 floor; LDS-read volume is data-volume-bound, so no further reduction
// without trading TLP (measured net-negative both directions).
__launch_bounds__(256, 4)
__global__ void k_gemm_select(const unsigned char* __restrict__ embq,
                              const float* __restrict__ sq,
                              const int* __restrict__ labels,
                              ull* __restrict__ best_pos,
                              ull* __restrict__ best_neg) {
  __shared__ __align__(16) unsigned char ldsA[BM * BK];  // 8 KB
  __shared__ __align__(16) unsigned char ldsB[BN * BK];  // 16 KB

  // linear bid -> (by in [0,64), bx in [0,32)) with bx*128+127 > by*64
  int rem = blockIdx.x, p = 0;
  while (rem >= 2 * (32 - p)) { rem -= 2 * (32 - p); ++p; }
  int by = 2 * p;
  int c = 32 - p;
  if (rem >= c) { by += 1; rem -= c; }
  const int bx = p + rem;

  const int tid  = threadIdx.x;
  const int lane = tid & 63;
  const int wave = tid >> 6;
  const int wm = wave >> 1, wn = wave & 1;
  const int q = lane >> 4, m15 = lane & 15;
  const int ibase = by * BM, jbase = bx * BN;

  // b128 fragment read offsets for slab-pair sh (slabs 2sh, 2sh+1), group g:
  //   row = wbase + g*16 + m15 ; chunk = q*2 + sh ; slot = chunk ^ (row&7)
  //   byte = row*128 + slot*16   (16-B aligned; [0,8)=slab 2sh, [8,16)=2sh+1)
  int aoff[2][2], boff[2][4];
#pragma unroll
  for (int sh = 0; sh < 2; ++sh) {
#pragma unroll
    for (int g = 0; g < 2; ++g) {
      int ra = wm * 32 + g * 16 + m15;
      aoff[sh][g] = ra * BK + (((q * 2 + sh) ^ (ra & 7)) * 16);
    }
#pragma unroll
    for (int g = 0; g < 4; ++g) {
      int rb = wn * 64 + g * 16 + m15;
      boff[sh][g] = rb * BK + (((q * 2 + sh) ^ (rb & 7)) * 16);
    }
  }

  // staging: 6 issues/wave per K-step (2 A + 4 B), 8 rows x 1 KB per issue.
  // LDS dest linear (base + lane*16); global source pre-swizzled so LDS slot
  // `slot` holds global chunk slot^(row&7)  (XOR involution matches reads).
  const int srow = lane >> 3;  // row within 8-row staging group
  const int slot = lane & 7;   // 16B slot within 128B row
  size_t agoff[2], bgoff[4];
  int lasta[2], lastb[4];
#pragma unroll
  for (int pp = 0; pp < 2; ++pp) {
    int r0  = wave * 16 + pp * 8;  // wave-uniform
    int row = r0 + srow;
    agoff[pp] = (size_t)(ibase + row) * D + (slot ^ (row & 7)) * 16;
    lasta[pp] = r0 * BK;
  }
#pragma unroll
  for (int pp = 0; pp < 4; ++pp) {
    int r0  = wave * 32 + pp * 8;  // wave-uniform
    int row = r0 + srow;
    bgoff[pp] = (size_t)(jbase + row) * D + (slot ^ (row & 7)) * 16;
    lastb[pp] = r0 * BK;
  }

  f32x4 acc[2][4];
  const f32x4 z = {0.f, 0.f, 0.f, 0.f};
#pragma unroll
  for (int a = 0; a < 2; ++a)
#pragma unroll
    for (int b = 0; b < 4; ++b) acc[a][b] = z;

  for (int kb = 0; kb < D; kb += BK) {
    __syncthreads();
#pragma unroll
    for (int pp = 0; pp < 2; ++pp)
      async_copy16(embq + agoff[pp] + kb, &ldsA[lasta[pp]]);
#pragma unroll
    for (int pp = 0; pp < 4; ++pp)
      async_copy16(embq + bgoff[pp] + kb, &ldsB[lastb[pp]]);
    __syncthreads();  // compiler emits vmcnt(0) drain before barrier

#pragma unroll
    for (int sh = 0; sh < 2; ++sh) {
      v2l af[2], bf[4];
#pragma unroll
      for (int g = 0; g < 2; ++g) af[g] = *(const v2l*)&ldsA[aoff[sh][g]];
#pragma unroll
      for (int g = 0; g < 4; ++g) bf[g] = *(const v2l*)&ldsB[boff[sh][g]];
#pragma unroll
      for (int mi = 0; mi < 2; ++mi)
#pragma unroll
        for (int ni = 0; ni < 4; ++ni)
          acc[mi][ni] = __builtin_amdgcn_mfma_f32_16x16x32_fp8_fp8(
              af[mi][0], bf[ni][0], acc[mi][ni], 0, 0, 0);
#pragma unroll
      for (int mi = 0; mi < 2; ++mi)
#pragma unroll
        for (int ni = 0; ni < 4; ++ni)
          acc[mi][ni] = __builtin_amdgcn_mfma_f32_16x16x32_fp8_fp8(
              af[mi][1], bf[ni][1], acc[mi][ni], 0, 0, 0);
    }
  }

  // ---- epilogue ----
  float sqj[4];
  int labj[4];
#pragma unroll
  for (int ni = 0; ni < 4; ++ni) {
    int jj = jbase + wn * 64 + ni * 16 + m15;
    sqj[ni] = sq[jj];
    labj[ni] = labels[jj];
  }

  ull colBp[4], colBn[4];
#pragma unroll
  for (int ni = 0; ni < 4; ++ni) { colBp[ni] = SENT_P; colBn[ni] = SENT_N; }

#pragma unroll
  for (int mi = 0; mi < 2; ++mi) {
#pragma unroll
    for (int r = 0; r < 4; ++r) {
      const int i = ibase + wm * 32 + mi * 16 + q * 4 + r;  // C/D row=(lane>>4)*4+r
      const float si = sq[i];
      const int li = labels[i];
      ull bp = SENT_P;
      ull bn = SENT_N;
#pragma unroll
      for (int ni = 0; ni < 4; ++ni) {
        int jj = jbase + wn * 64 + ni * 16 + m15;  // C/D col=lane&15
        if (jj > i) {                              // strict upper triangle only
          float dot = acc[mi][ni][r];
          float d2 = si + sqj[ni] - 2.0f * dot;
          float dist = sqrtf(fmaxf(d2, 0.0f));
          ull pv = ((ull)__float_as_uint(dist)) << 32;
          if (labj[ni] == li) {
            ull cr = pv | (unsigned)(~jj);  // max -> smallest idx wins ties
            bp = bp > cr ? bp : cr;
            ull cc = pv | (unsigned)(~i);
            colBp[ni] = colBp[ni] > cc ? colBp[ni] : cc;
          } else {
            ull cr = pv | (unsigned)jj;     // min -> smallest idx wins ties
            bn = bn < cr ? bn : cr;
            ull cc = pv | (unsigned)i;
            colBn[ni] = colBn[ni] < cc ? colBn[ni] : cc;
          }
        }
      }
      // row-i reduction across the 16 column lanes (m15 bits)
#pragma unroll
      for (int off = 1; off <= 8; off <<= 1) {
        ull op = __shfl_xor(bp, off, 64);
        ull on = __shfl_xor(bn, off, 64);
        bp = bp > op ? bp : op;
        bn = bn < on ? bn : on;
      }
      if (m15 == 0) {
        if (bp != SENT_P) atomicMax(&best_pos[i], bp);
        if (bn != SENT_N) atomicMin(&best_neg[i], bn);
      }
    }
  }

  // col-j reduction across the 4 q lane-groups
#pragma unroll
  for (int ni = 0; ni < 4; ++ni) {
    ull cp = colBp[ni], cn = colBn[ni];
#pragma unroll
    for (int off = 16; off <= 32; off <<= 1) {
      ull op = __shfl_xor(cp, off, 64);
      ull on = __shfl_xor(cn, off, 64);
      cp = cp > op ? cp : op;
      cn = cn < on ? cn : on;
    }
    if (q == 0) {
      int j = jbase + wn * 64 + ni * 16 + m15;
      if (cp != SENT_P) atomicMax(&best_pos[j], cp);
      if (cn != SENT_N) atomicMin(&best_neg[j], cn);
    }
  }
}

// ---------------- loss + finalize in one single-block kernel ----------------
__global__ void k_loss_final(const ull* __restrict__ best_pos,
                             const ull* __restrict__ best_neg,
                             const float* __restrict__ rs,
                             float* __restrict__ out) {
  float per = 0.0f;
  int v = 0;
  for (int i = threadIdx.x; i < B; i += 1024) {
    ull bp = best_pos[i], bn = best_neg[i];
    if (bp != SENT_P && bn != SENT_N) {
      unsigned pRaw = ~(unsigned)bp;
      unsigned nRaw = (unsigned)bn;
      int pi = pRaw < (unsigned)B ? (int)pRaw : 0;
      int ni = nRaw < (unsigned)B ? (int)nRaw : 0;
      float distp = __uint_as_float((unsigned)(bp >> 32));
      float distn = __uint_as_float((unsigned)(bn >> 32));
      float ri = rs[i];
      const float e = 1e-6f, de2 = (float)D * 1e-12f;
      float dp2 = distp * distp + 2.0f * e * (ri - rs[pi]) + de2;
      float dn2 = distn * distn + 2.0f * e * (ri - rs[ni]) + de2;
      float dp = sqrtf(fmaxf(dp2, 0.0f));
      float dn = sqrtf(fmaxf(dn2, 0.0f));
      per += fmaxf(dp - dn + 0.3f, 0.0f);
      v += 1;
    }
  }
  for (int off = 32; off; off >>= 1) {
    per += __shfl_down(per, off, 64);
    v   += __shfl_down(v, off, 64);
  }
  __shared__ float pps[16];
  __shared__ int pvs[16];
  int lane = threadIdx.x & 63, wave = threadIdx.x >> 6;
  if (lane == 0) { pps[wave] = per; pvs[wave] = v; }
  __syncthreads();
  if (threadIdx.x == 0) {
    float t = 0.f;
    int cv = 0;
#pragma unroll
    for (int w = 0; w < 16; ++w) { t += pps[w]; cv += pvs[w]; }
    out[0] = cv > 0 ? t / (float)cv : 0.0f;
  }
}

// ---------------- launch -----------------------------------------------------
extern "C" void kernel_launch(void* const* d_in, const int* in_sizes, int n_in,
                              void* d_out, int out_size, void* d_ws, size_t ws_size,
                              hipStream_t stream) {
  const float* emb = (const float*)d_in[0];
  const int* labels = (const int*)d_in[1];
  float* out = (float*)d_out;
  char* ws = (char*)d_ws;

  const size_t off_embq = 0;
  const size_t off_sq   = off_embq + (size_t)B * D;       // 8 MiB
  const size_t off_rs   = off_sq + (size_t)B * 4;
  const size_t off_bp   = off_rs + (size_t)B * 4;
  const size_t off_bn   = off_bp + (size_t)B * 8;

  unsigned char* embq = (unsigned char*)(ws + off_embq);
  float* sq   = (float*)(ws + off_sq);
  float* rs   = (float*)(ws + off_rs);
  ull* bp     = (ull*)(ws + off_bp);
  ull* bn     = (ull*)(ws + off_bn);

  hipLaunchKernelGGL(k_convert_sq, dim3(B), dim3(256), 0, stream,
                     emb, embq, sq, rs, bp, bn);
  hipLaunchKernelGGL(k_gemm_select, dim3(1056), dim3(256), 0, stream,
                     embq, sq, labels, bp, bn);
  hipLaunchKernelGGL(k_loss_final, dim3(1), dim3(1024), 0, stream,
                     bp, bn, rs, out);
}